// Round 1
// baseline (466.648 us; speedup 1.0000x reference)
//
#include <hip/hip_runtime.h>
#include <hip/hip_bf16.h>

#define NATC 10000
#define NNC 32
#define RSNC 16
#define THETANC 8
#define NEMBC 4
#define FEATC 576

// ---------------------------------------------------------------------------
// Kernel 1: per-atom descriptor (radial + angular) -> desc[NAT][576] in d_ws
// One block (256 threads) per atom.
// LDS: ux/uy/uz 384B + bf 2176B + se 640B + P 8KB + cos 4KB + sin 4KB
//      + A 32KB + ang 2KB = 54.4KB  -> 3 blocks/CU (12 waves/CU)
// ---------------------------------------------------------------------------
__global__ __launch_bounds__(256) void desc_kernel(
    const float* __restrict__ pos,
    const float* __restrict__ spe,
    const float* __restrict__ theta_s,
    const float* __restrict__ kn_rad,
    const int* __restrict__ nidx,
    float* __restrict__ desc)
{
    constexpr float RC = 5.0f;
    constexpr float PI_F = 3.14159265358979323846f;
    constexpr float PREF = 3.0517578125e-05f; // 2^(1-16)

    __shared__ float ux[NNC], uy[NNC], uz[NNC];
    __shared__ float bfs[NNC * 17];   // stride 17: conflict-free write+read
    __shared__ float ses[NNC * 5];    // stride 5
    __shared__ float P[NNC * 64];     // [j][p]  p = l*4+m
    __shared__ float cosm[NNC * NNC];
    __shared__ float sinm[NNC * NNC];
    __shared__ float A[THETANC * NNC * NNC]; // [t][j][k]
    __shared__ float ang[THETANC * 64];      // [t][p]

    const int i = blockIdx.x;
    const int tid = threadIdx.x;

    // zero the angular accumulator (512 floats)
    ang[tid] = 0.0f;
    ang[tid + 256] = 0.0f;

    if (tid < NNC) {
        const int j = tid;
        const int n = nidx[i * NNC + j];
        const float pix = pos[i * 3 + 0], piy = pos[i * 3 + 1], piz = pos[i * 3 + 2];
        const float dx = pos[n * 3 + 0] - pix;
        const float dy = pos[n * 3 + 1] - piy;
        const float dz = pos[n * 3 + 2] - piz;
        const float r = sqrtf(dx * dx + dy * dy + dz * dz) + 1e-8f;
        const float inv = 1.0f / r;
        ux[j] = dx * inv; uy[j] = dy * inv; uz[j] = dz * inv;
        const float fc = (r < RC) ? 0.5f * (cosf(PI_F * r * (1.0f / RC)) + 1.0f) : 0.0f;
        const float base = sqrtf(2.0f / RC) * inv * fc;
        const float w = (PI_F / RC) * kn_rad[0] * r;
        #pragma unroll
        for (int m = 0; m < NEMBC; ++m)
            ses[j * 5 + m] = spe[n * NEMBC + m] * spe[i * NEMBC + m];
        #pragma unroll
        for (int l = 0; l < RSNC; ++l)
            bfs[j * 17 + l] = base * sinf(w * (float)(l + 1));
    }
    __syncthreads();

    // P[j][p] = bf[j][p>>2] * se[j][p&3]   (2048 elems, 8/thread, coalesced)
    #pragma unroll
    for (int k = 0; k < 8; ++k) {
        const int e = tid + k * 256;
        const int j = e >> 6, p = e & 63;
        P[e] = bfs[j * 17 + (p >> 2)] * ses[j * 5 + (p & 3)];
    }

    // cos/sin between bond pairs (1024 elems, 4/thread)
    #pragma unroll
    for (int k = 0; k < 4; ++k) {
        const int idx = tid + k * 256;
        const int j = idx >> 5, kk = idx & 31;
        float c = ux[j] * ux[kk] + uy[j] * uy[kk] + uz[j] * uz[kk];
        c = fminf(fmaxf(c, -1.0f + 1e-6f), 1.0f - 1e-6f);
        cosm[idx] = c;
        sinm[idx] = sqrtf(fmaxf(1.0f - c * c, 0.0f));
    }
    __syncthreads();

    // A_t[j][k] = 2^-15 * (1 + cos(theta-theta_t))^16 ; 32 threads per t
    const int t = tid >> 5;
    const int local = tid & 31;
    {
        const float th = theta_s[t];
        const float ct = cosf(th), st = sinf(th);
        #pragma unroll 4
        for (int e = 0; e < 32; ++e) {
            const int idx = e * 32 + local;
            const float cosd = fmaf(cosm[idx], ct, sinm[idx] * st);
            const float x = 1.0f + cosd;
            const float x2 = x * x, x4 = x2 * x2, x8 = x4 * x4;
            A[t * 1024 + idx] = PREF * (x8 * x8);
        }
    }
    __syncthreads();

    // Contraction: B[k][p] = sum_j A_t[j][k] * P[j][p];
    // ang[t][p] = sum_k B[k][p] * P[k][p].
    // Thread tile: 8 k x 8 p (64 fp32 accumulators).
    const int k0 = (local >> 3) * 8;
    const int p0 = (local & 7) * 8;
    float acc[8][8];
    #pragma unroll
    for (int a = 0; a < 8; ++a)
        #pragma unroll
        for (int b = 0; b < 8; ++b) acc[a][b] = 0.0f;

    const float* At = &A[t * 1024];
    for (int j = 0; j < NNC; ++j) {
        float av[8], pv[8];
        #pragma unroll
        for (int u = 0; u < 8; ++u) av[u] = At[j * 32 + k0 + u];
        #pragma unroll
        for (int u = 0; u < 8; ++u) pv[u] = P[j * 64 + p0 + u];
        #pragma unroll
        for (int a = 0; a < 8; ++a)
            #pragma unroll
            for (int b = 0; b < 8; ++b)
                acc[a][b] = fmaf(av[a], pv[b], acc[a][b]);
    }
    float part[8];
    #pragma unroll
    for (int b = 0; b < 8; ++b) part[b] = 0.0f;
    #pragma unroll
    for (int a = 0; a < 8; ++a) {
        #pragma unroll
        for (int b = 0; b < 8; ++b)
            part[b] = fmaf(acc[a][b], P[(k0 + a) * 64 + p0 + b], part[b]);
    }
    #pragma unroll
    for (int b = 0; b < 8; ++b)
        atomicAdd(&ang[t * 64 + p0 + b], part[b]);
    __syncthreads();

    // desc_rad[p] = sum_j P[j][p]
    if (tid < 64) {
        float s = 0.0f;
        for (int j = 0; j < NNC; ++j) s += P[j * 64 + tid];
        desc[(size_t)i * FEATC + tid] = s;
    }
    desc[(size_t)i * FEATC + 64 + tid] = ang[tid];
    desc[(size_t)i * FEATC + 64 + 256 + tid] = ang[tid + 256];
}

// ---------------------------------------------------------------------------
// Kernel 2: per-atom MLP 576->64->64->1 (tanh), total-energy atomic sum.
// Block = 256 threads = 4 waves; wave g handles 8 atoms; lane j = out neuron.
// W1 rows streamed coalesced; desc chunks staged in 8KB LDS.
// ---------------------------------------------------------------------------
__global__ __launch_bounds__(256) void mlp_kernel(
    const float* __restrict__ desc,
    const float* __restrict__ W1, const float* __restrict__ b1,
    const float* __restrict__ W2, const float* __restrict__ b2,
    const float* __restrict__ W3, const float* __restrict__ b3,
    float* __restrict__ out)
{
    __shared__ float buf[32 * 64]; // desc chunk, then h1
    const int tid = threadIdx.x;
    const int j = tid & 63;
    const int g = tid >> 6;
    const int ablock = blockIdx.x * 32;

    float acc[8];
    const float bj1 = b1[j];
    #pragma unroll
    for (int q = 0; q < 8; ++q) acc[q] = bj1;

    for (int c = 0; c < 9; ++c) {
        __syncthreads();
        #pragma unroll
        for (int k = 0; k < 8; ++k) {
            const int e = tid + k * 256;
            const int at = e >> 6, p = e & 63;
            const int a = ablock + at;
            buf[e] = (a < NATC) ? desc[(size_t)a * FEATC + c * 64 + p] : 0.0f;
        }
        __syncthreads();
        #pragma unroll 4
        for (int p = 0; p < 64; ++p) {
            const float w = W1[(c * 64 + p) * 64 + j];
            #pragma unroll
            for (int q = 0; q < 8; ++q)
                acc[q] = fmaf(buf[(g * 8 + q) * 64 + p], w, acc[q]);
        }
    }
    __syncthreads();
    #pragma unroll
    for (int q = 0; q < 8; ++q)
        buf[(g * 8 + q) * 64 + j] = tanhf(acc[q]);
    __syncthreads();

    float acc2[8];
    const float bj2 = b2[j];
    #pragma unroll
    for (int q = 0; q < 8; ++q) acc2[q] = bj2;
    #pragma unroll 4
    for (int p = 0; p < 64; ++p) {
        const float w = W2[p * 64 + j];
        #pragma unroll
        for (int q = 0; q < 8; ++q)
            acc2[q] = fmaf(buf[(g * 8 + q) * 64 + p], w, acc2[q]);
    }
    const float w3 = W3[j];
    float s = 0.0f;
    int nv = 0;
    #pragma unroll
    for (int q = 0; q < 8; ++q) {
        const int a = ablock + g * 8 + q;
        if (a < NATC) { s += tanhf(acc2[q]) * w3; ++nv; }
    }
    #pragma unroll
    for (int off = 32; off > 0; off >>= 1)
        s += __shfl_xor(s, off, 64);
    if (j == 0) atomicAdd(out, s + (float)nv * b3[0]);
}

extern "C" void kernel_launch(void* const* d_in, const int* in_sizes, int n_in,
                              void* d_out, int out_size, void* d_ws, size_t ws_size,
                              hipStream_t stream)
{
    const float* pos   = (const float*)d_in[0];
    const float* spe   = (const float*)d_in[1];
    const float* theta = (const float*)d_in[2];
    const float* kn    = (const float*)d_in[3];
    const float* W1    = (const float*)d_in[4];
    const float* b1    = (const float*)d_in[5];
    const float* W2    = (const float*)d_in[6];
    const float* b2    = (const float*)d_in[7];
    const float* W3    = (const float*)d_in[8];
    const float* b3    = (const float*)d_in[9];
    const int*   nidx  = (const int*)d_in[10];
    float* out = (float*)d_out;
    float* desc = (float*)d_ws; // 10000*576*4 = 23.04 MB scratch

    hipMemsetAsync(out, 0, sizeof(float), stream);
    desc_kernel<<<NATC, 256, 0, stream>>>(pos, spe, theta, kn, nidx, desc);
    mlp_kernel<<<(NATC + 31) / 32, 256, 0, stream>>>(desc, W1, b1, W2, b2, W3, b3, out);
}

// Round 2
// 355.043 us; speedup vs baseline: 1.3143x; 1.3143x over previous
//
#include <hip/hip_runtime.h>
#include <hip/hip_bf16.h>

#define NATC 10000
#define NNC 32
#define RSNC 16
#define THETANC 8
#define NEMBC 4
#define FEATC 576

// ---------------------------------------------------------------------------
// Kernel 1: per-atom descriptor. TWO blocks per atom (4 theta-centers each).
// 256 threads; theta group = 64 threads; thread tile 4k x 8p (32 fp32 acc).
// LDS ~36.2 KB -> 4 blocks/CU (16 waves/CU, 50% occupancy).
// ---------------------------------------------------------------------------
__global__ __launch_bounds__(256, 4) void desc_kernel(
    const float* __restrict__ pos,
    const float* __restrict__ spe,
    const float* __restrict__ theta_s,
    const float* __restrict__ kn_rad,
    const int* __restrict__ nidx,
    float* __restrict__ desc)
{
    constexpr float RC = 5.0f;
    constexpr float PI_F = 3.14159265358979323846f;
    constexpr float PREF = 3.0517578125e-05f; // 2^(1-16)

    __shared__ __attribute__((aligned(16))) float ux[NNC], uy[NNC], uz[NNC];
    __shared__ __attribute__((aligned(16))) float rbase[NNC], rw[NNC];
    __shared__ __attribute__((aligned(16))) float bfs[NNC * 17];
    __shared__ __attribute__((aligned(16))) float ses[NNC * 5];
    __shared__ __attribute__((aligned(16))) float P[NNC * 64];        // [j][p]
    __shared__ __attribute__((aligned(16))) float cosm[NNC * NNC];
    __shared__ __attribute__((aligned(16))) float sinm[NNC * NNC];
    __shared__ __attribute__((aligned(16))) float A[4 * NNC * NNC];   // [tg][j][k]

    const int bid  = blockIdx.x;
    const int i    = bid >> 1;        // atom
    const int half = bid & 1;         // theta half: 0 -> t 0..3, 1 -> t 4..7
    const int tid  = threadIdx.x;

    // --- bond geometry (32 threads) ---
    if (tid < NNC) {
        const int j = tid;
        const int n = nidx[i * NNC + j];
        const float pix = pos[i * 3 + 0], piy = pos[i * 3 + 1], piz = pos[i * 3 + 2];
        const float dx = pos[n * 3 + 0] - pix;
        const float dy = pos[n * 3 + 1] - piy;
        const float dz = pos[n * 3 + 2] - piz;
        const float r = sqrtf(dx * dx + dy * dy + dz * dz) + 1e-8f;
        const float inv = 1.0f / r;
        ux[j] = dx * inv; uy[j] = dy * inv; uz[j] = dz * inv;
        const float fc = (r < RC) ? 0.5f * (cosf(PI_F * r * (1.0f / RC)) + 1.0f) : 0.0f;
        rbase[j] = sqrtf(2.0f / RC) * inv * fc;
        rw[j]    = (PI_F / RC) * kn_rad[0] * r;
        #pragma unroll
        for (int m = 0; m < NEMBC; ++m)
            ses[j * 5 + m] = spe[n * NEMBC + m] * spe[i * NEMBC + m];
    }
    __syncthreads();

    // --- bessel radial basis (512 work items over 256 threads) ---
    #pragma unroll
    for (int k = 0; k < 2; ++k) {
        const int e = tid + k * 256;
        const int j = e >> 4, l = e & 15;
        bfs[j * 17 + l] = rbase[j] * sinf(rw[j] * (float)(l + 1));
    }
    __syncthreads();

    // --- P[j][p] = bf[j][p>>2] * se[j][p&3] ---
    #pragma unroll
    for (int k = 0; k < 8; ++k) {
        const int e = tid + k * 256;
        const int j = e >> 6, p = e & 63;
        P[e] = bfs[j * 17 + (p >> 2)] * ses[j * 5 + (p & 3)];
    }

    // --- bond-pair cos/sin (1024 items) ---
    #pragma unroll
    for (int k = 0; k < 4; ++k) {
        const int idx = tid + k * 256;
        const int j = idx >> 5, kk = idx & 31;
        float c = ux[j] * ux[kk] + uy[j] * uy[kk] + uz[j] * uz[kk];
        c = fminf(fmaxf(c, -1.0f + 1e-6f), 1.0f - 1e-6f);
        cosm[idx] = c;
        sinm[idx] = sqrtf(fmaxf(1.0f - c * c, 0.0f));
    }
    __syncthreads();

    // --- A_tg[j][k] = 2^-15 (1 + cos(theta - theta_t))^16 ---
    const int tg    = tid >> 6;        // local theta 0..3
    const int t     = half * 4 + tg;   // global theta 0..7
    const int local = tid & 63;
    {
        const float th = theta_s[t];
        const float ct = cosf(th), st = sinf(th);
        #pragma unroll 4
        for (int e = 0; e < 16; ++e) {
            const int idx = e * 64 + local;
            const float cosd = fmaf(cosm[idx], ct, sinm[idx] * st);
            const float x = 1.0f + cosd;
            const float x2 = x * x, x4 = x2 * x2, x8 = x4 * x4;
            A[tg * 1024 + idx] = PREF * (x8 * x8);
        }
    }
    __syncthreads();

    // --- contraction: B[k][p] = sum_j A[j][k] P[j][p]; ang[p] = sum_k B[k][p] P[k][p]
    const int k0 = ((local >> 3) & 7) << 2;   // 0,4,...,28
    const int p0 = (local & 7) << 3;          // 0,8,...,56
    float acc[4][8];
    #pragma unroll
    for (int a = 0; a < 4; ++a)
        #pragma unroll
        for (int b = 0; b < 8; ++b) acc[a][b] = 0.0f;

    const float* At = &A[tg * 1024];
    #pragma unroll 2
    for (int j = 0; j < NNC; ++j) {
        float av[4], pv[8];
        #pragma unroll
        for (int u = 0; u < 4; ++u) av[u] = At[j * 32 + k0 + u];
        #pragma unroll
        for (int u = 0; u < 8; ++u) pv[u] = P[j * 64 + p0 + u];
        #pragma unroll
        for (int a = 0; a < 4; ++a)
            #pragma unroll
            for (int b = 0; b < 8; ++b)
                acc[a][b] = fmaf(av[a], pv[b], acc[a][b]);
    }

    float part[8];
    #pragma unroll
    for (int b = 0; b < 8; ++b) part[b] = 0.0f;
    #pragma unroll
    for (int a = 0; a < 4; ++a) {
        #pragma unroll
        for (int b = 0; b < 8; ++b)
            part[b] = fmaf(acc[a][b], P[(k0 + a) * 64 + p0 + b], part[b]);
    }
    // reduce over the 8 k-groups: lanes differing in bits 3..5 of `local`
    #pragma unroll
    for (int b = 0; b < 8; ++b) {
        part[b] += __shfl_xor(part[b], 8, 64);
        part[b] += __shfl_xor(part[b], 16, 64);
        part[b] += __shfl_xor(part[b], 32, 64);
    }
    if ((local >> 3) == 0) {
        float4* dst = (float4*)&desc[(size_t)i * FEATC + 64 + t * 64 + p0];
        dst[0] = make_float4(part[0], part[1], part[2], part[3]);
        dst[1] = make_float4(part[4], part[5], part[6], part[7]);
    }

    // --- radial descriptor (half 0 only) ---
    if (half == 0 && tid < 64) {
        float s = 0.0f;
        #pragma unroll 8
        for (int j = 0; j < NNC; ++j) s += P[j * 64 + tid];
        desc[(size_t)i * FEATC + tid] = s;
    }
}

// ---------------------------------------------------------------------------
// Kernel 2: per-atom MLP 576->64->64->1 (tanh) + total-energy atomic sum.
// 8 atoms per block (grid 1250). Wave g handles 2 atoms; lane j = neuron.
// ---------------------------------------------------------------------------
__global__ __launch_bounds__(256) void mlp_kernel(
    const float* __restrict__ desc,
    const float* __restrict__ W1, const float* __restrict__ b1,
    const float* __restrict__ W2, const float* __restrict__ b2,
    const float* __restrict__ W3, const float* __restrict__ b3,
    float* __restrict__ out)
{
    __shared__ float buf[8 * 64];     // desc chunk, then h1
    const int tid = threadIdx.x;
    const int j = tid & 63;
    const int g = tid >> 6;
    const int ablock = blockIdx.x * 8;

    float acc[2];
    const float bj1 = b1[j];
    acc[0] = bj1; acc[1] = bj1;

    for (int c = 0; c < 9; ++c) {
        __syncthreads();
        #pragma unroll
        for (int k = 0; k < 2; ++k) {
            const int e = tid + k * 256;
            const int at = e >> 6, p = e & 63;
            buf[e] = desc[(size_t)(ablock + at) * FEATC + c * 64 + p];
        }
        __syncthreads();
        #pragma unroll 8
        for (int p = 0; p < 64; ++p) {
            const float w = W1[(c * 64 + p) * 64 + j];
            acc[0] = fmaf(buf[(g * 2 + 0) * 64 + p], w, acc[0]);
            acc[1] = fmaf(buf[(g * 2 + 1) * 64 + p], w, acc[1]);
        }
    }
    __syncthreads();
    buf[(g * 2 + 0) * 64 + j] = tanhf(acc[0]);
    buf[(g * 2 + 1) * 64 + j] = tanhf(acc[1]);
    __syncthreads();

    float acc2[2];
    const float bj2 = b2[j];
    acc2[0] = bj2; acc2[1] = bj2;
    #pragma unroll 8
    for (int p = 0; p < 64; ++p) {
        const float w = W2[p * 64 + j];
        acc2[0] = fmaf(buf[(g * 2 + 0) * 64 + p], w, acc2[0]);
        acc2[1] = fmaf(buf[(g * 2 + 1) * 64 + p], w, acc2[1]);
    }
    const float w3 = W3[j];
    float s = (tanhf(acc2[0]) + tanhf(acc2[1])) * w3;
    #pragma unroll
    for (int off = 32; off > 0; off >>= 1)
        s += __shfl_xor(s, off, 64);
    if (j == 0) atomicAdd(out, s + 2.0f * b3[0]);
}

extern "C" void kernel_launch(void* const* d_in, const int* in_sizes, int n_in,
                              void* d_out, int out_size, void* d_ws, size_t ws_size,
                              hipStream_t stream)
{
    const float* pos   = (const float*)d_in[0];
    const float* spe   = (const float*)d_in[1];
    const float* theta = (const float*)d_in[2];
    const float* kn    = (const float*)d_in[3];
    const float* W1    = (const float*)d_in[4];
    const float* b1    = (const float*)d_in[5];
    const float* W2    = (const float*)d_in[6];
    const float* b2    = (const float*)d_in[7];
    const float* W3    = (const float*)d_in[8];
    const float* b3    = (const float*)d_in[9];
    const int*   nidx  = (const int*)d_in[10];
    float* out = (float*)d_out;
    float* desc = (float*)d_ws; // 10000*576*4 = 23.04 MB scratch

    hipMemsetAsync(out, 0, sizeof(float), stream);
    desc_kernel<<<NATC * 2, 256, 0, stream>>>(pos, spe, theta, kn, nidx, desc);
    mlp_kernel<<<NATC / 8, 256, 0, stream>>>(desc, W1, b1, W2, b2, W3, b3, out);
}

// Round 3
// 302.449 us; speedup vs baseline: 1.5429x; 1.1739x over previous
//
#include <hip/hip_runtime.h>
#include <hip/hip_bf16.h>

#define NATC 10000
#define NNC 32
#define RSNC 16
#define THETANC 8
#define NEMBC 4
#define FEATC 576

// ---------------------------------------------------------------------------
// Kernel 1: per-atom descriptor. TWO blocks per atom (4 theta-centers each).
// (unchanged from round 2: 36.2 KB LDS -> 4 blocks/CU, VALUBusy ~81%)
// ---------------------------------------------------------------------------
__global__ __launch_bounds__(256, 4) void desc_kernel(
    const float* __restrict__ pos,
    const float* __restrict__ spe,
    const float* __restrict__ theta_s,
    const float* __restrict__ kn_rad,
    const int* __restrict__ nidx,
    float* __restrict__ desc)
{
    constexpr float RC = 5.0f;
    constexpr float PI_F = 3.14159265358979323846f;
    constexpr float PREF = 3.0517578125e-05f; // 2^(1-16)

    __shared__ __attribute__((aligned(16))) float ux[NNC], uy[NNC], uz[NNC];
    __shared__ __attribute__((aligned(16))) float rbase[NNC], rw[NNC];
    __shared__ __attribute__((aligned(16))) float bfs[NNC * 17];
    __shared__ __attribute__((aligned(16))) float ses[NNC * 5];
    __shared__ __attribute__((aligned(16))) float P[NNC * 64];        // [j][p]
    __shared__ __attribute__((aligned(16))) float cosm[NNC * NNC];
    __shared__ __attribute__((aligned(16))) float sinm[NNC * NNC];
    __shared__ __attribute__((aligned(16))) float A[4 * NNC * NNC];   // [tg][j][k]

    const int bid  = blockIdx.x;
    const int i    = bid >> 1;        // atom
    const int half = bid & 1;         // theta half
    const int tid  = threadIdx.x;

    if (tid < NNC) {
        const int j = tid;
        const int n = nidx[i * NNC + j];
        const float pix = pos[i * 3 + 0], piy = pos[i * 3 + 1], piz = pos[i * 3 + 2];
        const float dx = pos[n * 3 + 0] - pix;
        const float dy = pos[n * 3 + 1] - piy;
        const float dz = pos[n * 3 + 2] - piz;
        const float r = sqrtf(dx * dx + dy * dy + dz * dz) + 1e-8f;
        const float inv = 1.0f / r;
        ux[j] = dx * inv; uy[j] = dy * inv; uz[j] = dz * inv;
        const float fc = (r < RC) ? 0.5f * (cosf(PI_F * r * (1.0f / RC)) + 1.0f) : 0.0f;
        rbase[j] = sqrtf(2.0f / RC) * inv * fc;
        rw[j]    = (PI_F / RC) * kn_rad[0] * r;
        #pragma unroll
        for (int m = 0; m < NEMBC; ++m)
            ses[j * 5 + m] = spe[n * NEMBC + m] * spe[i * NEMBC + m];
    }
    __syncthreads();

    #pragma unroll
    for (int k = 0; k < 2; ++k) {
        const int e = tid + k * 256;
        const int j = e >> 4, l = e & 15;
        bfs[j * 17 + l] = rbase[j] * sinf(rw[j] * (float)(l + 1));
    }
    __syncthreads();

    #pragma unroll
    for (int k = 0; k < 8; ++k) {
        const int e = tid + k * 256;
        const int j = e >> 6, p = e & 63;
        P[e] = bfs[j * 17 + (p >> 2)] * ses[j * 5 + (p & 3)];
    }

    #pragma unroll
    for (int k = 0; k < 4; ++k) {
        const int idx = tid + k * 256;
        const int j = idx >> 5, kk = idx & 31;
        float c = ux[j] * ux[kk] + uy[j] * uy[kk] + uz[j] * uz[kk];
        c = fminf(fmaxf(c, -1.0f + 1e-6f), 1.0f - 1e-6f);
        cosm[idx] = c;
        sinm[idx] = sqrtf(fmaxf(1.0f - c * c, 0.0f));
    }
    __syncthreads();

    const int tg    = tid >> 6;
    const int t     = half * 4 + tg;
    const int local = tid & 63;
    {
        const float th = theta_s[t];
        const float ct = cosf(th), st = sinf(th);
        #pragma unroll 4
        for (int e = 0; e < 16; ++e) {
            const int idx = e * 64 + local;
            const float cosd = fmaf(cosm[idx], ct, sinm[idx] * st);
            const float x = 1.0f + cosd;
            const float x2 = x * x, x4 = x2 * x2, x8 = x4 * x4;
            A[tg * 1024 + idx] = PREF * (x8 * x8);
        }
    }
    __syncthreads();

    const int k0 = ((local >> 3) & 7) << 2;
    const int p0 = (local & 7) << 3;
    float acc[4][8];
    #pragma unroll
    for (int a = 0; a < 4; ++a)
        #pragma unroll
        for (int b = 0; b < 8; ++b) acc[a][b] = 0.0f;

    const float* At = &A[tg * 1024];
    #pragma unroll 2
    for (int j = 0; j < NNC; ++j) {
        float av[4], pv[8];
        #pragma unroll
        for (int u = 0; u < 4; ++u) av[u] = At[j * 32 + k0 + u];
        #pragma unroll
        for (int u = 0; u < 8; ++u) pv[u] = P[j * 64 + p0 + u];
        #pragma unroll
        for (int a = 0; a < 4; ++a)
            #pragma unroll
            for (int b = 0; b < 8; ++b)
                acc[a][b] = fmaf(av[a], pv[b], acc[a][b]);
    }

    float part[8];
    #pragma unroll
    for (int b = 0; b < 8; ++b) part[b] = 0.0f;
    #pragma unroll
    for (int a = 0; a < 4; ++a) {
        #pragma unroll
        for (int b = 0; b < 8; ++b)
            part[b] = fmaf(acc[a][b], P[(k0 + a) * 64 + p0 + b], part[b]);
    }
    #pragma unroll
    for (int b = 0; b < 8; ++b) {
        part[b] += __shfl_xor(part[b], 8, 64);
        part[b] += __shfl_xor(part[b], 16, 64);
        part[b] += __shfl_xor(part[b], 32, 64);
    }
    if ((local >> 3) == 0) {
        float4* dst = (float4*)&desc[(size_t)i * FEATC + 64 + t * 64 + p0];
        dst[0] = make_float4(part[0], part[1], part[2], part[3]);
        dst[1] = make_float4(part[4], part[5], part[6], part[7]);
    }

    if (half == 0 && tid < 64) {
        float s = 0.0f;
        #pragma unroll 8
        for (int j = 0; j < NNC; ++j) s += P[j * 64 + tid];
        desc[(size_t)i * FEATC + tid] = s;
    }
}

// ---------------------------------------------------------------------------
// Kernel 2 (REWRITTEN): LDS-tiled GEMM MLP. 32 atoms/block, 256 threads.
// Thread tile = 2 atoms x 4 neurons. W chunk 16 KB + desc chunk (pad 68) in
// LDS; inner loop = 2x ds_read_b128 (W) + 2x ds_read_b64 (desc, broadcast)
// + 16 FMA. One atomic per block.
// ---------------------------------------------------------------------------
__global__ __launch_bounds__(256) void mlp_kernel(
    const float* __restrict__ desc,
    const float* __restrict__ W1, const float* __restrict__ b1,
    const float* __restrict__ W2, const float* __restrict__ b2,
    const float* __restrict__ W3, const float* __restrict__ b3,
    float* __restrict__ out)
{
    __shared__ __attribute__((aligned(16))) float Wc[64 * 64];   // 16 KB
    __shared__ __attribute__((aligned(16))) float Dc[32 * 68];   // 8.5 KB
    __shared__ float red[4];

    const int tid = threadIdx.x;
    const int ng  = tid & 15;          // neuron group -> n0 = ng*4
    const int ag  = tid >> 4;          // atom group -> atoms ag*2, ag*2+1
    const int n0  = ng * 4;
    const int aA  = ag * 2, aB = ag * 2 + 1;
    const int a0  = blockIdx.x * 32;

    float acc[2][4];
    #pragma unroll
    for (int q = 0; q < 4; ++q) {
        const float b = b1[n0 + q];
        acc[0][q] = b; acc[1][q] = b;
    }

    // ---- layer 1: 576 -> 64, in 9 chunks of 64 features ----
    for (int c = 0; c < 9; ++c) {
        __syncthreads();
        #pragma unroll
        for (int it = 0; it < 16; ++it) {
            const int e = tid + it * 256;
            Wc[e] = W1[c * 4096 + e];                 // [(c*64+k)*64 + n]
        }
        #pragma unroll
        for (int it = 0; it < 8; ++it) {
            const int e = tid + it * 256;
            const int a = e >> 6, k = e & 63;
            const int ga = a0 + a;
            Dc[a * 68 + k] = (ga < NATC) ? desc[(size_t)ga * FEATC + c * 64 + k] : 0.0f;
        }
        __syncthreads();
        #pragma unroll 4
        for (int k = 0; k < 64; k += 2) {
            const float4 w0 = *(const float4*)&Wc[k * 64 + n0];
            const float4 w1 = *(const float4*)&Wc[(k + 1) * 64 + n0];
            const float2 dA = *(const float2*)&Dc[aA * 68 + k];
            const float2 dB = *(const float2*)&Dc[aB * 68 + k];
            acc[0][0] = fmaf(dA.x, w0.x, acc[0][0]); acc[0][1] = fmaf(dA.x, w0.y, acc[0][1]);
            acc[0][2] = fmaf(dA.x, w0.z, acc[0][2]); acc[0][3] = fmaf(dA.x, w0.w, acc[0][3]);
            acc[1][0] = fmaf(dB.x, w0.x, acc[1][0]); acc[1][1] = fmaf(dB.x, w0.y, acc[1][1]);
            acc[1][2] = fmaf(dB.x, w0.z, acc[1][2]); acc[1][3] = fmaf(dB.x, w0.w, acc[1][3]);
            acc[0][0] = fmaf(dA.y, w1.x, acc[0][0]); acc[0][1] = fmaf(dA.y, w1.y, acc[0][1]);
            acc[0][2] = fmaf(dA.y, w1.z, acc[0][2]); acc[0][3] = fmaf(dA.y, w1.w, acc[0][3]);
            acc[1][0] = fmaf(dB.y, w1.x, acc[1][0]); acc[1][1] = fmaf(dB.y, w1.y, acc[1][1]);
            acc[1][2] = fmaf(dB.y, w1.z, acc[1][2]); acc[1][3] = fmaf(dB.y, w1.w, acc[1][3]);
        }
    }

    // ---- tanh, write H1 back to Dc; stage W2 ----
    __syncthreads();
    {
        float4 hA, hB;
        hA.x = tanhf(acc[0][0]); hA.y = tanhf(acc[0][1]);
        hA.z = tanhf(acc[0][2]); hA.w = tanhf(acc[0][3]);
        hB.x = tanhf(acc[1][0]); hB.y = tanhf(acc[1][1]);
        hB.z = tanhf(acc[1][2]); hB.w = tanhf(acc[1][3]);
        *(float4*)&Dc[aA * 68 + n0] = hA;
        *(float4*)&Dc[aB * 68 + n0] = hB;
    }
    #pragma unroll
    for (int it = 0; it < 16; ++it) {
        const int e = tid + it * 256;
        Wc[e] = W2[e];
    }
    __syncthreads();

    // ---- layer 2: 64 -> 64 ----
    float acc2[2][4];
    #pragma unroll
    for (int q = 0; q < 4; ++q) {
        const float b = b2[n0 + q];
        acc2[0][q] = b; acc2[1][q] = b;
    }
    #pragma unroll 4
    for (int k = 0; k < 64; k += 2) {
        const float4 w0 = *(const float4*)&Wc[k * 64 + n0];
        const float4 w1 = *(const float4*)&Wc[(k + 1) * 64 + n0];
        const float2 dA = *(const float2*)&Dc[aA * 68 + k];
        const float2 dB = *(const float2*)&Dc[aB * 68 + k];
        acc2[0][0] = fmaf(dA.x, w0.x, acc2[0][0]); acc2[0][1] = fmaf(dA.x, w0.y, acc2[0][1]);
        acc2[0][2] = fmaf(dA.x, w0.z, acc2[0][2]); acc2[0][3] = fmaf(dA.x, w0.w, acc2[0][3]);
        acc2[1][0] = fmaf(dB.x, w0.x, acc2[1][0]); acc2[1][1] = fmaf(dB.x, w0.y, acc2[1][1]);
        acc2[1][2] = fmaf(dB.x, w0.z, acc2[1][2]); acc2[1][3] = fmaf(dB.x, w0.w, acc2[1][3]);
        acc2[0][0] = fmaf(dA.y, w1.x, acc2[0][0]); acc2[0][1] = fmaf(dA.y, w1.y, acc2[0][1]);
        acc2[0][2] = fmaf(dA.y, w1.z, acc2[0][2]); acc2[0][3] = fmaf(dA.y, w1.w, acc2[0][3]);
        acc2[1][0] = fmaf(dB.y, w1.x, acc2[1][0]); acc2[1][1] = fmaf(dB.y, w1.y, acc2[1][1]);
        acc2[1][2] = fmaf(dB.y, w1.z, acc2[1][2]); acc2[1][3] = fmaf(dB.y, w1.w, acc2[1][3]);
    }

    // ---- layer 3 + masked reduction ----
    float sA = 0.0f, sB = 0.0f;
    #pragma unroll
    for (int q = 0; q < 4; ++q) {
        const float w3 = W3[n0 + q];
        sA = fmaf(tanhf(acc2[0][q]), w3, sA);
        sB = fmaf(tanhf(acc2[1][q]), w3, sB);
    }
    if (a0 + aA >= NATC) sA = 0.0f;
    if (a0 + aB >= NATC) sB = 0.0f;
    float s = sA + sB;
    #pragma unroll
    for (int off = 1; off <= 32; off <<= 1)
        s += __shfl_xor(s, off, 64);
    if ((tid & 63) == 0) red[tid >> 6] = s;
    __syncthreads();
    if (tid == 0) {
        float tot = red[0] + red[1] + red[2] + red[3];
        if (blockIdx.x == 0) tot += (float)NATC * b3[0];
        atomicAdd(out, tot);
    }
}

extern "C" void kernel_launch(void* const* d_in, const int* in_sizes, int n_in,
                              void* d_out, int out_size, void* d_ws, size_t ws_size,
                              hipStream_t stream)
{
    const float* pos   = (const float*)d_in[0];
    const float* spe   = (const float*)d_in[1];
    const float* theta = (const float*)d_in[2];
    const float* kn    = (const float*)d_in[3];
    const float* W1    = (const float*)d_in[4];
    const float* b1    = (const float*)d_in[5];
    const float* W2    = (const float*)d_in[6];
    const float* b2    = (const float*)d_in[7];
    const float* W3    = (const float*)d_in[8];
    const float* b3    = (const float*)d_in[9];
    const int*   nidx  = (const int*)d_in[10];
    float* out = (float*)d_out;
    float* desc = (float*)d_ws; // 10000*576*4 = 23.04 MB scratch

    hipMemsetAsync(out, 0, sizeof(float), stream);
    desc_kernel<<<NATC * 2, 256, 0, stream>>>(pos, spe, theta, kn, nidx, desc);
    mlp_kernel<<<(NATC + 31) / 32, 256, 0, stream>>>(desc, W1, b1, W2, b2, W3, b3, out);
}

// Round 4
// 154.340 us; speedup vs baseline: 3.0235x; 1.9596x over previous
//
#include <hip/hip_runtime.h>
#include <hip/hip_bf16.h>

#define NATC 10000
#define NATP 10016          // padded atom count for MFMA m-tiles
#define NNC 32
#define RSNC 16
#define THETANC 8
#define NEMBC 4
#define FEATC 576

typedef __attribute__((ext_vector_type(8))) short short8;  // 8 bf16 (4 VGPRs)
typedef __attribute__((ext_vector_type(4))) float f32x4;

static __device__ __forceinline__ short f2bf(float x) {
    union { __hip_bfloat16 h; short s; } u;
    u.h = __float2bfloat16(x);
    return u.s;
}

// ---------------------------------------------------------------------------
// Kernel 0: pack W1 (576x64) and W2 (64x64) into bf16 MFMA B-fragment order.
// B-frag for 16x16x32: lane l needs W[k = ks*32 + (l>>4)*8 + jj][n = nt*16 + (l&15)]
// stored contiguously: Wp[((ks*4+nt)*64 + l)*8 + jj].
// ---------------------------------------------------------------------------
__global__ __launch_bounds__(256) void prep_kernel(
    const float* __restrict__ W1, const float* __restrict__ W2,
    ushort* __restrict__ W1p, ushort* __restrict__ W2p)
{
    const int gid = blockIdx.x * 256 + threadIdx.x;   // 0..5119
    if (gid < 4608) {                                 // W1: 18 ks * 4 nt * 64 l
        const int l = gid & 63, ntks = gid >> 6;
        const int nt = ntks & 3, ks = ntks >> 2;
        const int q = l >> 4, c = l & 15;
        ushort pk[8];
        #pragma unroll
        for (int jj = 0; jj < 8; ++jj)
            pk[jj] = (ushort)f2bf(W1[(ks * 32 + q * 8 + jj) * 64 + nt * 16 + c]);
        #pragma unroll
        for (int jj = 0; jj < 8; ++jj) W1p[gid * 8 + jj] = pk[jj];
    } else {                                          // W2: 2 ks * 4 nt * 64 l
        const int g = gid - 4608;
        const int l = g & 63, ntks = g >> 6;
        const int nt = ntks & 3, ks = ntks >> 2;
        const int q = l >> 4, c = l & 15;
        ushort pk[8];
        #pragma unroll
        for (int jj = 0; jj < 8; ++jj)
            pk[jj] = (ushort)f2bf(W2[(ks * 32 + q * 8 + jj) * 64 + nt * 16 + c]);
        #pragma unroll
        for (int jj = 0; jj < 8; ++jj) W2p[g * 8 + jj] = pk[jj];
    }
}

// ---------------------------------------------------------------------------
// Kernel 1: per-atom descriptor via MFMA. One block (256 thr) per atom.
// Wave w handles theta {w, w+4}. Per theta: 2 m-tiles x 4 n-tiles of
// mfma_f32_16x16x32_bf16 computing B[k][p] = sum_j A[j][k] P[j][p].
// A-fragments built in registers from cosm/sinm (symmetric, pad-33 stride).
// P: fp32 copy (stride 65) for epilogue/radial + bf16 copy packed in exact
// B-fragment order (1 ds_read_b128 per fragment).
// LDS = 640+2176+640+8320+8448+4096 = 24320 B -> 5-6 blocks/CU.
// Output desc is bf16 [NATP][576].
// ---------------------------------------------------------------------------
__global__ __launch_bounds__(256, 4) void desc_kernel(
    const float* __restrict__ pos,
    const float* __restrict__ spe,
    const float* __restrict__ theta_s,
    const float* __restrict__ kn_rad,
    const int* __restrict__ nidx,
    ushort* __restrict__ descb)
{
    constexpr float RC = 5.0f;
    constexpr float PI_F = 3.14159265358979323846f;
    constexpr float PREF = 3.0517578125e-05f; // 2^(1-16)

    __shared__ __attribute__((aligned(16))) float ux[NNC], uy[NNC], uz[NNC];
    __shared__ __attribute__((aligned(16))) float rbase[NNC], rw[NNC];
    __shared__ __attribute__((aligned(16))) float bfs[NNC * 17];
    __shared__ __attribute__((aligned(16))) float ses[NNC * 5];
    __shared__ __attribute__((aligned(16))) float P[NNC * 65];      // fp32, pad 65
    __shared__ __attribute__((aligned(16))) float cosm[NNC * 33];   // pad 33
    __shared__ __attribute__((aligned(16))) float sinm[NNC * 33];
    __shared__ __attribute__((aligned(16))) short Pb[4 * 64 * 8];   // bf16 B-frags

    const int i   = blockIdx.x;
    const int tid = threadIdx.x;

    // --- phase 0: bond geometry (32 threads) ---
    if (tid < NNC) {
        const int j = tid;
        const int n = nidx[i * NNC + j];
        const float pix = pos[i * 3 + 0], piy = pos[i * 3 + 1], piz = pos[i * 3 + 2];
        const float dx = pos[n * 3 + 0] - pix;
        const float dy = pos[n * 3 + 1] - piy;
        const float dz = pos[n * 3 + 2] - piz;
        const float r = sqrtf(dx * dx + dy * dy + dz * dz) + 1e-8f;
        const float inv = 1.0f / r;
        ux[j] = dx * inv; uy[j] = dy * inv; uz[j] = dz * inv;
        const float fc = (r < RC) ? 0.5f * (cosf(PI_F * r * (1.0f / RC)) + 1.0f) : 0.0f;
        rbase[j] = sqrtf(2.0f / RC) * inv * fc;
        rw[j]    = (PI_F / RC) * kn_rad[0] * r;
        #pragma unroll
        for (int m = 0; m < NEMBC; ++m)
            ses[j * 5 + m] = spe[n * NEMBC + m] * spe[i * NEMBC + m];
    }
    __syncthreads();

    // --- phase 1: bessel basis (512 items) ---
    #pragma unroll
    for (int k = 0; k < 2; ++k) {
        const int e = tid + k * 256;
        const int j = e >> 4, l = e & 15;
        bfs[j * 17 + l] = rbase[j] * sinf(rw[j] * (float)(l + 1));
    }
    __syncthreads();

    // --- phase 2: P fp32 (stride 65) + cos/sin matrix (stride 33) ---
    #pragma unroll
    for (int k = 0; k < 8; ++k) {
        const int e = tid + k * 256;
        const int j = e >> 6, p = e & 63;
        P[j * 65 + p] = bfs[j * 17 + (p >> 2)] * ses[j * 5 + (p & 3)];
    }
    #pragma unroll
    for (int k = 0; k < 4; ++k) {
        const int idx = tid + k * 256;
        const int j = idx >> 5, kk = idx & 31;
        float c = ux[j] * ux[kk] + uy[j] * uy[kk] + uz[j] * uz[kk];
        c = fminf(fmaxf(c, -1.0f + 1e-6f), 1.0f - 1e-6f);
        cosm[j * 33 + kk] = c;
        sinm[j * 33 + kk] = sqrtf(fmaxf(1.0f - c * c, 0.0f));
    }
    __syncthreads();

    // --- phase 3: pack Pb (bf16 B-fragments) + radial descriptor ---
    {
        const int nt = tid >> 6, l2 = tid & 63;
        const int q2 = l2 >> 4, c2 = l2 & 15;
        short8 pk;
        #pragma unroll
        for (int jj = 0; jj < 8; ++jj)
            pk[jj] = f2bf(P[(q2 * 8 + jj) * 65 + nt * 16 + c2]);
        *(short8*)&Pb[(nt * 64 + l2) * 8] = pk;
    }
    if (tid < 64) {
        float s = 0.0f;
        #pragma unroll 8
        for (int j = 0; j < NNC; ++j) s += P[j * 65 + tid];
        descb[(size_t)i * FEATC + tid] = (ushort)f2bf(s);
    }
    __syncthreads();

    // --- phase 4: MFMA contraction per theta ---
    const int w = tid >> 6, l = tid & 63;
    const int q = l >> 4, c = l & 15;

    for (int tt = 0; tt < 2; ++tt) {
        const int t = w + tt * 4;
        const float th = theta_s[t];
        const float ct = cosf(th), st = sinf(th);

        // A-fragments: A_op[m=k-idx][kk=j] = A[j][k] built in registers.
        short8 afr[2];
        #pragma unroll
        for (int mt = 0; mt < 2; ++mt) {
            const int kk = mt * 16 + c;
            #pragma unroll
            for (int jj = 0; jj < 8; ++jj) {
                const int j = q * 8 + jj;
                const float cv = cosm[kk * 33 + j];
                const float sv = sinm[kk * 33 + j];
                const float cosd = fmaf(cv, ct, sv * st);
                const float x = 1.0f + cosd;
                const float x2 = x * x, x4 = x2 * x2, x8 = x4 * x4;
                afr[mt][jj] = f2bf(PREF * (x8 * x8));
            }
        }

        f32x4 acc[2][4];
        #pragma unroll
        for (int mt = 0; mt < 2; ++mt)
            #pragma unroll
            for (int nt = 0; nt < 4; ++nt)
                acc[mt][nt] = (f32x4){0.0f, 0.0f, 0.0f, 0.0f};

        #pragma unroll
        for (int nt = 0; nt < 4; ++nt) {
            const short8 bfr = *(const short8*)&Pb[(nt * 64 + l) * 8];
            acc[0][nt] = __builtin_amdgcn_mfma_f32_16x16x32_bf16(afr[0], bfr, acc[0][nt], 0, 0, 0);
            acc[1][nt] = __builtin_amdgcn_mfma_f32_16x16x32_bf16(afr[1], bfr, acc[1][nt], 0, 0, 0);
        }

        // epilogue: ang[p] = sum_k B[k][p] * P[k][p]; k spread over quads+regs
        float pt[4];
        #pragma unroll
        for (int nt = 0; nt < 4; ++nt) {
            float s = 0.0f;
            #pragma unroll
            for (int mt = 0; mt < 2; ++mt)
                #pragma unroll
                for (int r = 0; r < 4; ++r) {
                    const int kk = mt * 16 + q * 4 + r;
                    s = fmaf(acc[mt][nt][r], P[kk * 65 + nt * 16 + c], s);
                }
            s += __shfl_xor(s, 16, 64);
            s += __shfl_xor(s, 32, 64);
            pt[nt] = s;
        }
        const float v = (q == 0) ? pt[0] : (q == 1) ? pt[1] : (q == 2) ? pt[2] : pt[3];
        descb[(size_t)i * FEATC + 64 + t * 64 + l] = (ushort)f2bf(v);
    }
}

// ---------------------------------------------------------------------------
// Kernel 2: MFMA MLP. 32 atoms/block (grid 313), wave w = n-tile.
// Layer1: 18 K-steps, A-frags straight from global descb (bf16), B from W1p.
// Layer2 via LDS H1 (bf16, stride 72 for 16B-aligned frag loads).
// Layer3: tanh*W3, full wave reduce, 1 atomic/block. OOB atoms masked.
// ---------------------------------------------------------------------------
__global__ __launch_bounds__(256) void mlp_kernel(
    const ushort* __restrict__ descb,
    const ushort* __restrict__ W1p, const float* __restrict__ b1,
    const ushort* __restrict__ W2p, const float* __restrict__ b2,
    const float* __restrict__ W3, const float* __restrict__ b3,
    float* __restrict__ out)
{
    __shared__ __attribute__((aligned(16))) ushort H1b[32 * 72];
    __shared__ float red[4];

    const int tid = threadIdx.x;
    const int w = tid >> 6, l = tid & 63;
    const int q = l >> 4, c = l & 15;
    const int a0 = blockIdx.x * 32;

    f32x4 acc[2];
    acc[0] = (f32x4){0.0f, 0.0f, 0.0f, 0.0f};
    acc[1] = (f32x4){0.0f, 0.0f, 0.0f, 0.0f};

    #pragma unroll 3
    for (int ks = 0; ks < 18; ++ks) {
        const short8 b = *(const short8*)&W1p[((ks * 4 + w) * 64 + l) * 8];
        #pragma unroll
        for (int mt = 0; mt < 2; ++mt) {
            const int a = a0 + mt * 16 + c;   // < NATP (padded), poison rows masked later
            const short8 afr = *(const short8*)&descb[(size_t)a * FEATC + ks * 32 + q * 8];
            acc[mt] = __builtin_amdgcn_mfma_f32_16x16x32_bf16(afr, b, acc[mt], 0, 0, 0);
        }
    }

    const float b1v = b1[w * 16 + c];
    #pragma unroll
    for (int mt = 0; mt < 2; ++mt)
        #pragma unroll
        for (int r = 0; r < 4; ++r) {
            const int m = mt * 16 + q * 4 + r;          // atom-local row
            H1b[m * 72 + w * 16 + c] = (ushort)f2bf(tanhf(acc[mt][r] + b1v));
        }
    __syncthreads();

    f32x4 acc2[2];
    acc2[0] = (f32x4){0.0f, 0.0f, 0.0f, 0.0f};
    acc2[1] = (f32x4){0.0f, 0.0f, 0.0f, 0.0f};
    #pragma unroll
    for (int ks = 0; ks < 2; ++ks) {
        const short8 b = *(const short8*)&W2p[((ks * 4 + w) * 64 + l) * 8];
        #pragma unroll
        for (int mt = 0; mt < 2; ++mt) {
            const short8 afr = *(const short8*)&H1b[(mt * 16 + c) * 72 + ks * 32 + q * 8];
            acc2[mt] = __builtin_amdgcn_mfma_f32_16x16x32_bf16(afr, b, acc2[mt], 0, 0, 0);
        }
    }

    const float b2v = b2[w * 16 + c];
    const float w3v = W3[w * 16 + c];
    float s = 0.0f;
    #pragma unroll
    for (int mt = 0; mt < 2; ++mt)
        #pragma unroll
        for (int r = 0; r < 4; ++r) {
            const int a = a0 + mt * 16 + q * 4 + r;
            const float e = tanhf(acc2[mt][r] + b2v) * w3v;
            if (a < NATC) s += e;
        }
    #pragma unroll
    for (int off = 1; off <= 32; off <<= 1)
        s += __shfl_xor(s, off, 64);
    if (l == 0) red[w] = s;
    __syncthreads();
    if (tid == 0) {
        float tot = red[0] + red[1] + red[2] + red[3];
        if (blockIdx.x == 0) tot += (float)NATC * b3[0];
        atomicAdd(out, tot);
    }
}

extern "C" void kernel_launch(void* const* d_in, const int* in_sizes, int n_in,
                              void* d_out, int out_size, void* d_ws, size_t ws_size,
                              hipStream_t stream)
{
    const float* pos   = (const float*)d_in[0];
    const float* spe   = (const float*)d_in[1];
    const float* theta = (const float*)d_in[2];
    const float* kn    = (const float*)d_in[3];
    const float* W1    = (const float*)d_in[4];
    const float* b1    = (const float*)d_in[5];
    const float* W2    = (const float*)d_in[6];
    const float* b2    = (const float*)d_in[7];
    const float* W3    = (const float*)d_in[8];
    const float* b3    = (const float*)d_in[9];
    const int*   nidx  = (const int*)d_in[10];
    float* out = (float*)d_out;

    // workspace layout (bytes): descb [NATP*576 u16] | W1p [36864 u16] | W2p [4096 u16]
    ushort* descb = (ushort*)d_ws;
    ushort* W1p   = (ushort*)((char*)d_ws + (size_t)NATP * FEATC * 2);   // 11,538,432
    ushort* W2p   = W1p + 4608 * 8;

    hipMemsetAsync(out, 0, sizeof(float), stream);
    prep_kernel<<<20, 256, 0, stream>>>(W1, W2, W1p, W2p);
    desc_kernel<<<NATC, 256, 0, stream>>>(pos, spe, theta, kn, nidx, descb);
    mlp_kernel<<<(NATC + 31) / 32, 256, 0, stream>>>(descb, W1p, b1, W2p, b2, W3, b3, out);
}